// Round 1
// baseline (36477.292 us; speedup 1.0000x reference)
//
#include <hip/hip_runtime.h>
#include <cmath>

#define BB 128
#define TT 512
#define II 256
#define HH 1024

typedef _Float16 half4v __attribute__((ext_vector_type(4)));
typedef _Float16 half8  __attribute__((ext_vector_type(8)));
typedef float    f32x4  __attribute__((ext_vector_type(4)));

__device__ __forceinline__ float sigmoidf_(float x) { return 1.0f / (1.0f + __expf(-x)); }

// ---- convert x to fp16 ----
__global__ __launch_bounds__(256) void cvt_x_kernel(const float* __restrict__ x,
                                                    _Float16* __restrict__ x16, int n4) {
  int i = blockIdx.x * blockDim.x + threadIdx.x;
  if (i >= n4) return;
  const float4 v = ((const float4*)x)[i];
  half4v o = { (_Float16)v.x, (_Float16)v.y, (_Float16)v.z, (_Float16)v.w };
  ((half4v*)x16)[i] = o;
}

// ---- build gate-interleaved fp16 weight [4096][Kin+HH]; row' = 4*j + gate ----
__global__ __launch_bounds__(256) void prep_w_kernel(const float* __restrict__ Wih,
    const float* __restrict__ Whh, const float* __restrict__ bih, const float* __restrict__ bhh,
    _Float16* __restrict__ Wr, float* __restrict__ biasr, int Kin) {
  const int Ktot = Kin + HH;
  const int row  = blockIdx.y;
  const int k    = blockIdx.x * blockDim.x + threadIdx.x;
  const int jj = row >> 2, gate = row & 3;
  const int orow = gate * HH + jj;
  if (k < Ktot) {
    float v = (k < Kin) ? Wih[(size_t)orow * Kin + k] : Whh[(size_t)orow * HH + (k - Kin)];
    Wr[(size_t)row * Ktot + k] = (_Float16)v;
  }
  if (blockIdx.x == 0 && threadIdx.x == 0) biasr[row] = bih[orow] + bhh[orow];
}

// ---- one timestep, both layers (z=0: layer0 step tau; z=1: layer1 step tau-1) ----
// Grid (64, 4, 2), block 256 (4 waves). Wave tile: 16 gate-rows x 32 batch-cols.
// D[4096][128] = Wr[4096][K] @ concat(x_t|h_prev)[K][128]; epilogue = lane-local cell update.
__global__ __launch_bounds__(256) void lstm_step(
    const _Float16* __restrict__ w0r, const _Float16* __restrict__ w1r,
    const float* __restrict__ bias0, const float* __restrict__ bias1,
    const _Float16* __restrict__ x16,
    _Float16* __restrict__ h0buf, float* __restrict__ c0,
    _Float16* __restrict__ h1buf, float* __restrict__ c1,
    int tau)
{
  const int lane = threadIdx.x & 63;
  const int wave = threadIdx.x >> 6;
  const int l15  = lane & 15;
  const int kl   = lane >> 4;

  int K, lowLen;
  size_t lowStride;
  const _Float16 *W, *srcLow, *srcHigh;
  const float* bias;
  _Float16* hOut;
  float* cState;

  if (blockIdx.z == 0) {
    if (tau >= TT) return;
    K = II + HH; lowLen = II; lowStride = (size_t)TT * II;
    W = w0r; bias = bias0;
    srcLow  = x16 + (size_t)tau * II;                   // x[b][tau][k], stride T*I per b
    srcHigh = h0buf + ((tau + 1) & 1) * (BB * HH);      // h0_{tau-1}
    hOut    = h0buf + (tau & 1) * (BB * HH);            // h0_tau
    cState  = c0;
  } else {
    const int t = tau - 1;
    if (t < 0) return;
    K = 2 * HH; lowLen = HH; lowStride = HH;
    W = w1r; bias = bias1;
    srcLow  = h0buf + (t & 1) * (BB * HH);              // h0_t (written last launch)
    srcHigh = h1buf + ((t + 1) & 1) * (BB * HH);        // h1_{t-1}
    hOut    = h1buf + (t & 1) * (BB * HH);              // h1_t
    cState  = c1;
  }

  const int mb = blockIdx.x * 64 + wave * 16;   // gate-row base (reordered rows = 4*j+gate)
  const int nb = blockIdx.y * 32;               // batch base
  const int b0 = nb + l15;
  const int b1 = nb + 16 + l15;

  f32x4 acc0 = {0.f,0.f,0.f,0.f}, acc1 = {0.f,0.f,0.f,0.f};

  const _Float16* Arow = W + (size_t)(mb + l15) * K + kl * 4;
  const _Float16* low0 = srcLow + (size_t)b0 * lowStride + kl * 4;
  const _Float16* low1 = srcLow + (size_t)b1 * lowStride + kl * 4;
  const _Float16* hi0  = srcHigh + (size_t)b0 * HH + kl * 4;
  const _Float16* hi1  = srcHigh + (size_t)b1 * HH + kl * 4;

  union H8 { half8 v8; half4v v4[2]; };

  int k0 = 0;
  #pragma unroll 2
  for (; k0 < lowLen; k0 += 32) {
    H8 a, v0, v1;
    a.v4[0]  = *(const half4v*)(Arow + k0);
    a.v4[1]  = *(const half4v*)(Arow + k0 + 16);
    v0.v4[0] = *(const half4v*)(low0 + k0);
    v0.v4[1] = *(const half4v*)(low0 + k0 + 16);
    v1.v4[0] = *(const half4v*)(low1 + k0);
    v1.v4[1] = *(const half4v*)(low1 + k0 + 16);
    acc0 = __builtin_amdgcn_mfma_f32_16x16x32_f16(a.v8, v0.v8, acc0, 0, 0, 0);
    acc1 = __builtin_amdgcn_mfma_f32_16x16x32_f16(a.v8, v1.v8, acc1, 0, 0, 0);
  }
  #pragma unroll 2
  for (; k0 < K; k0 += 32) {
    const int kh = k0 - lowLen;
    H8 a, v0, v1;
    a.v4[0]  = *(const half4v*)(Arow + k0);
    a.v4[1]  = *(const half4v*)(Arow + k0 + 16);
    v0.v4[0] = *(const half4v*)(hi0 + kh);
    v0.v4[1] = *(const half4v*)(hi0 + kh + 16);
    v1.v4[0] = *(const half4v*)(hi1 + kh);
    v1.v4[1] = *(const half4v*)(hi1 + kh + 16);
    acc0 = __builtin_amdgcn_mfma_f32_16x16x32_f16(a.v8, v0.v8, acc0, 0, 0, 0);
    acc1 = __builtin_amdgcn_mfma_f32_16x16x32_f16(a.v8, v1.v8, acc1, 0, 0, 0);
  }

  // Epilogue: lane holds rows mb + kl*4 + r (r = gate 0..3 = i,f,g,o), hidden j = mb/4 + kl
  const int j = (mb >> 2) + kl;
  const f32x4 bs = *(const f32x4*)(bias + mb + kl * 4);

  {
    float gi = sigmoidf_(acc0[0] + bs[0]);
    float gf = sigmoidf_(acc0[1] + bs[1]);
    float gg = tanhf(acc0[2] + bs[2]);
    float go = sigmoidf_(acc0[3] + bs[3]);
    size_t idx = (size_t)b0 * HH + j;
    float cn = gf * cState[idx] + gi * gg;
    cState[idx] = cn;
    hOut[idx] = (_Float16)(go * tanhf(cn));
  }
  {
    float gi = sigmoidf_(acc1[0] + bs[0]);
    float gf = sigmoidf_(acc1[1] + bs[1]);
    float gg = tanhf(acc1[2] + bs[2]);
    float go = sigmoidf_(acc1[3] + bs[3]);
    size_t idx = (size_t)b1 * HH + j;
    float cn = gf * cState[idx] + gi * gg;
    cState[idx] = cn;
    hOut[idx] = (_Float16)(go * tanhf(cn));
  }
}

// ---- final projection: out[b][o] = h1_last[b] . Wfc[o] + bfc[o] ----
__global__ __launch_bounds__(128) void fc_kernel(const _Float16* __restrict__ h,
    const float* __restrict__ Wfc, const float* __restrict__ bfc, float* __restrict__ out) {
  const int b = blockIdx.x;
  const int o = threadIdx.x;
  const _Float16* hr = h + (size_t)b * HH;
  const float* wr = Wfc + (size_t)o * HH;
  float s = 0.f;
  #pragma unroll 4
  for (int k = 0; k < HH; k += 4) {
    float4 w = *(const float4*)(wr + k);
    half4v hv = *(const half4v*)(hr + k);
    s += (float)hv[0]*w.x + (float)hv[1]*w.y + (float)hv[2]*w.z + (float)hv[3]*w.w;
  }
  out[(size_t)b * 128 + o] = s + bfc[o];
}

extern "C" void kernel_launch(void* const* d_in, const int* in_sizes, int n_in,
                              void* d_out, int out_size, void* d_ws, size_t ws_size,
                              hipStream_t stream) {
  const float* x    = (const float*)d_in[0];
  const float* Wih0 = (const float*)d_in[1];
  const float* Whh0 = (const float*)d_in[2];
  const float* bih0 = (const float*)d_in[3];
  const float* bhh0 = (const float*)d_in[4];
  const float* Wih1 = (const float*)d_in[5];
  const float* Whh1 = (const float*)d_in[6];
  const float* bih1 = (const float*)d_in[7];
  const float* bhh1 = (const float*)d_in[8];
  const float* Wfc  = (const float*)d_in[9];
  const float* bfc  = (const float*)d_in[10];
  float* out = (float*)d_out;

  char* ws = (char*)d_ws;
  size_t off = 0;
  auto alloc = [&](size_t bytes) -> void* {
    void* p = ws + off;
    off += (bytes + 255) & ~(size_t)255;
    return p;
  };
  _Float16* x16 = (_Float16*)alloc((size_t)BB * TT * II * 2);
  _Float16* w0r = (_Float16*)alloc((size_t)4096 * 1280 * 2);
  _Float16* w1r = (_Float16*)alloc((size_t)4096 * 2048 * 2);
  float* bias0  = (float*)alloc(4096 * 4);
  float* bias1  = (float*)alloc(4096 * 4);
  const size_t stateBytes = (size_t)2*BB*HH*2 + 2*BB*HH*2 + BB*HH*4 + BB*HH*4;
  char* states  = (char*)alloc(stateBytes);
  _Float16* h0buf = (_Float16*)states;
  _Float16* h1buf = h0buf + 2 * BB * HH;
  float* c0 = (float*)(h1buf + 2 * BB * HH);
  float* c1 = c0 + BB * HH;

  hipMemsetAsync(states, 0, stateBytes, stream);

  {
    int n4 = BB * TT * II / 4;
    cvt_x_kernel<<<dim3((n4 + 255) / 256), 256, 0, stream>>>(x, x16, n4);
  }
  prep_w_kernel<<<dim3((1280 + 255) / 256, 4096), 256, 0, stream>>>(Wih0, Whh0, bih0, bhh0, w0r, bias0, II);
  prep_w_kernel<<<dim3((2048 + 255) / 256, 4096), 256, 0, stream>>>(Wih1, Whh1, bih1, bhh1, w1r, bias1, HH);

  for (int tau = 0; tau <= TT; ++tau) {
    lstm_step<<<dim3(64, 4, 2), 256, 0, stream>>>(w0r, w1r, bias0, bias1, x16,
                                                  h0buf, c0, h1buf, c1, tau);
  }

  fc_kernel<<<dim3(BB), 128, 0, stream>>>(h1buf + ((TT - 1) & 1) * BB * HH, Wfc, bfc, out);
}